// Round 2
// baseline (321.327 us; speedup 1.0000x reference)
//
#include <hip/hip_runtime.h>
#include <hip/hip_bf16.h>

typedef __attribute__((ext_vector_type(8))) short bfx8;
typedef __attribute__((ext_vector_type(4))) short bfx4;
typedef __attribute__((ext_vector_type(4))) float f32x4;
typedef __attribute__((ext_vector_type(4))) unsigned int u32x4;

#define T_SEQ 4096
#define C_DIM 768
#define NH    12
#define HD    64
#define QKV_N 2304

#define MFMA16(a, b, c) __builtin_amdgcn_mfma_f32_16x16x32_bf16((a), (b), (c), 0, 0, 0)

__device__ __forceinline__ short f2bf(float f) {
  __hip_bfloat16 h = __float2bfloat16(f);
  return __builtin_bit_cast(short, h);
}

__device__ __forceinline__ unsigned pack_bf2(float a, float b) {
  unsigned lo = (unsigned short)f2bf(a);
  unsigned hi = (unsigned short)f2bf(b);
  return (hi << 16) | lo;
}

// ---------------- f32 -> bf16 convert (vectorized) ----------------
__global__ __launch_bounds__(256) void conv_bf16_kernel(
    const float* __restrict__ in, short* __restrict__ out, int n4) {
  int i = blockIdx.x * 256 + threadIdx.x;
  if (i >= n4) return;
  float4 v = ((const float4*)in)[i];
  bfx4 o;
  o[0] = f2bf(v.x); o[1] = f2bf(v.y); o[2] = f2bf(v.z); o[3] = f2bf(v.w);
  ((bfx4*)out)[i] = o;
}

// ------------- f32 [R][Cc] -> bf16 transposed [Cc][R] -------------
__global__ __launch_bounds__(256) void transpose_bf16_kernel(
    const float* __restrict__ in, short* __restrict__ out, int R, int Cc) {
  __shared__ short tile[32][33];
  int bx = blockIdx.x * 32, by = blockIdx.y * 32;
  int tx = threadIdx.x & 31, ty = threadIdx.x >> 5;  // 32x8
#pragma unroll
  for (int i = 0; i < 32; i += 8)
    tile[ty + i][tx] = f2bf(in[(size_t)(by + ty + i) * Cc + (bx + tx)]);
  __syncthreads();
#pragma unroll
  for (int i = 0; i < 32; i += 8)
    out[(size_t)(bx + ty + i) * R + (by + tx)] = tile[tx][ty + i];
}

// ---------------- bf16 GEMM: C[M][N] = A[M][K] * Bt[N][K]^T ----------------
// m97-style: 128x128 tile, BK=32, 4 waves (2x2 of 64x64), global_load_lds w=16.
template <bool OUT_BF16>
__global__ __launch_bounds__(256) void gemm_bf16(
    const short* __restrict__ A, const short* __restrict__ Bt,
    void* __restrict__ C, int M, int N, int K) {
  __shared__ short As[128 * 32];
  __shared__ short Bs[128 * 32];
  const int tid  = threadIdx.x;
  const int lane = tid & 63;
  const int wave = tid >> 6;
  const int am0 = blockIdx.x * 128;
  const int bn0 = blockIdx.y * 128;
  const int wr = (wave >> 1) * 64;
  const int wc = (wave & 1) * 64;

  const f32x4 zero = {0.f, 0.f, 0.f, 0.f};
  f32x4 acc[4][4];
#pragma unroll
  for (int i = 0; i < 4; i++)
#pragma unroll
    for (int j = 0; j < 4; j++) acc[i][j] = zero;

  for (int k0 = 0; k0 < K; k0 += 32) {
#pragma unroll
    for (int i = 0; i < 2; i++) {
      int idx = i * 256 + tid;
      int r = idx >> 2;
      int c = (idx & 3) * 8;
      __builtin_amdgcn_global_load_lds(
          (const __attribute__((address_space(1))) void*)(A + (size_t)(am0 + r) * K + k0 + c),
          (__attribute__((address_space(3))) void*)(As + idx * 8), 16, 0, 0);
      __builtin_amdgcn_global_load_lds(
          (const __attribute__((address_space(1))) void*)(Bt + (size_t)(bn0 + r) * K + k0 + c),
          (__attribute__((address_space(3))) void*)(Bs + idx * 8), 16, 0, 0);
    }
    __syncthreads();  // drains vmcnt -> staged data visible

    bfx8 a[4], b[4];
#pragma unroll
    for (int mf = 0; mf < 4; mf++)
      a[mf] = *(const bfx8*)&As[(wr + mf * 16 + (lane & 15)) * 32 + (lane >> 4) * 8];
#pragma unroll
    for (int nf = 0; nf < 4; nf++)
      b[nf] = *(const bfx8*)&Bs[(wc + nf * 16 + (lane & 15)) * 32 + (lane >> 4) * 8];
#pragma unroll
    for (int mf = 0; mf < 4; mf++)
#pragma unroll
      for (int nf = 0; nf < 4; nf++)
        acc[mf][nf] = MFMA16(a[mf], b[nf], acc[mf][nf]);
    __syncthreads();  // all reads done before next stage overwrites
  }

  // epilogue: C/D layout col=lane&15, row=(lane>>4)*4+reg  [m89]
#pragma unroll
  for (int mf = 0; mf < 4; mf++) {
#pragma unroll
    for (int r = 0; r < 4; r++) {
      int row = am0 + wr + mf * 16 + (lane >> 4) * 4 + r;
#pragma unroll
      for (int nf = 0; nf < 4; nf++) {
        int col = bn0 + wc + nf * 16 + (lane & 15);
        float v = acc[mf][nf][r];
        if (OUT_BF16)
          ((short*)C)[(size_t)row * N + col] = f2bf(v);
        else
          ((float*)C)[(size_t)row * N + col] = v;
      }
    }
  }
}

// ---------------- causal flash attention ----------------
// 4 waves/block, each wave owns 16 q-rows; KVBLK=32.
// Swapped QK^T: S^T = mfma(K, Q), so lane (g=lane>>4, q=lane&15) holds
//   s_lo[r] = S^T[key=kv+4g+r][q],  s_hi[r] = S^T[key=kv+16+4g+r][q].
// PV (O^T = V^T * P^T, 16x16x32) needs B-frag pf8[j] = P[key=kv+8g+j][q];
// built via 8 ds_bpermute: fetch from src lanes (g&1)*32+q and +16,
// selecting lo-tile P when g<2 else hi-tile P.
__global__ __launch_bounds__(256) void attn_kernel(
    const short* __restrict__ qkv, short* __restrict__ yb) {
  const int lane = threadIdx.x & 63;
  const int wv   = threadIdx.x >> 6;
  const int h    = blockIdx.y;
  const int q0   = blockIdx.x * 64 + wv * 16;
  const int col  = lane & 15;  // q index within tile
  const int g    = lane >> 4;  // lane group

  const int hq = h * HD;
  const int hk = C_DIM + h * HD;
  const int hv = 2 * C_DIM + h * HD;

  // Q fragments (B-operand of swapped QK^T): lane holds Q[q0+col][g*8+j]
  bfx8 qf0 = *(const bfx8*)&qkv[(size_t)(q0 + col) * QKV_N + hq + g * 8];
  bfx8 qf1 = *(const bfx8*)&qkv[(size_t)(q0 + col) * QKV_N + hq + 32 + g * 8];

  const f32x4 zero = {0.f, 0.f, 0.f, 0.f};
  f32x4 o[4];
#pragma unroll
  for (int c = 0; c < 4; c++) o[c] = zero;
  float m = -INFINITY, lsum = 0.f;

  const int qabs = q0 + col;
  const int src0 = (g & 1) * 32 + col;
  const int src1 = src0 + 16;

  for (int kv = 0; kv < q0 + 16; kv += 32) {
    // K fragments (A-operand): row = lane&15 -> key, k = g*8+j -> d
    const short* krl = &qkv[(size_t)(kv + col) * QKV_N + hk];
    const short* krh = &qkv[(size_t)(kv + 16 + col) * QKV_N + hk];
    bfx8 kl0 = *(const bfx8*)&krl[g * 8];
    bfx8 kl1 = *(const bfx8*)&krl[32 + g * 8];
    bfx8 kh0 = *(const bfx8*)&krh[g * 8];
    bfx8 kh1 = *(const bfx8*)&krh[32 + g * 8];

    f32x4 slo = zero, shi = zero;
    slo = MFMA16(kl0, qf0, slo);
    slo = MFMA16(kl1, qf1, slo);
    shi = MFMA16(kh0, qf0, shi);
    shi = MFMA16(kh1, qf1, shi);

    float sv[8];
#pragma unroll
    for (int r = 0; r < 4; r++) {
      int key_lo = kv + 4 * g + r;
      int key_hi = key_lo + 16;
      sv[r]     = (key_lo > qabs) ? -INFINITY : slo[r] * 0.125f;
      sv[4 + r] = (key_hi > qabs) ? -INFINITY : shi[r] * 0.125f;
    }
    float tm = sv[0];
#pragma unroll
    for (int r = 1; r < 8; r++) tm = fmaxf(tm, sv[r]);
    tm = fmaxf(tm, __shfl_xor(tm, 16));
    tm = fmaxf(tm, __shfl_xor(tm, 32));
    float mnew = fmaxf(m, tm);
    float scale_old = __expf(m - mnew);  // 0 on first tile (m = -inf)

    float p[8], psum = 0.f;
#pragma unroll
    for (int r = 0; r < 8; r++) {
      p[r] = __expf(sv[r] - mnew);
      psum += p[r];
    }
    psum += __shfl_xor(psum, 16);
    psum += __shfl_xor(psum, 32);
    lsum = lsum * scale_old + psum;
    m = mnew;

    // pack own P into bf16 pairs
    unsigned L0 = pack_bf2(p[0], p[1]);
    unsigned L1 = pack_bf2(p[2], p[3]);
    unsigned H0 = pack_bf2(p[4], p[5]);
    unsigned H1 = pack_bf2(p[6], p[7]);

    // redistribute: receiver (g,q) takes {L or H} word pairs from src0, src1
    unsigned a0 = __shfl(L0, src0, 64), b0 = __shfl(H0, src0, 64);
    unsigned a1 = __shfl(L1, src0, 64), b1 = __shfl(H1, src0, 64);
    unsigned a2 = __shfl(L0, src1, 64), b2 = __shfl(H0, src1, 64);
    unsigned a3 = __shfl(L1, src1, 64), b3 = __shfl(H1, src1, 64);
    u32x4 w;
    w[0] = (g < 2) ? a0 : b0;
    w[1] = (g < 2) ? a1 : b1;
    w[2] = (g < 2) ? a2 : b2;
    w[3] = (g < 2) ? a3 : b3;
    bfx8 pf = __builtin_bit_cast(bfx8, w);

    // rescale accumulated O before adding this tile
#pragma unroll
    for (int c = 0; c < 4; c++)
#pragma unroll
      for (int r = 0; r < 4; r++) o[c][r] *= scale_old;

    // PV: O^T[d][q] += V^T[d][key] * P^T[key][q]; d in 4 chunks of 16
    // A-frag: row = lane&15 -> d within chunk, k = g*8+j -> key
#pragma unroll
    for (int c = 0; c < 4; c++) {
      bfx8 vf;
#pragma unroll
      for (int j = 0; j < 8; j++)
        vf[j] = qkv[(size_t)(kv + g * 8 + j) * QKV_N + hv + c * 16 + col];
      o[c] = MFMA16(vf, pf, o[c]);
    }
  }

  float inv = 1.f / lsum;
#pragma unroll
  for (int c = 0; c < 4; c++) {
    bfx4 ov;
#pragma unroll
    for (int r = 0; r < 4; r++) ov[r] = f2bf(o[c][r] * inv);
    // lane holds O[q=q0+col][d = c*16 + g*4 + r] -> 4 consecutive d: 8B store
    *(bfx4*)&yb[(size_t)(q0 + col) * C_DIM + h * HD + c * 16 + g * 4] = ov;
  }
}

// ---------------- launch ----------------
extern "C" void kernel_launch(void* const* d_in, const int* in_sizes, int n_in,
                              void* d_out, int out_size, void* d_ws, size_t ws_size,
                              hipStream_t stream) {
  const float* x      = (const float*)d_in[0];
  const float* w_attn = (const float*)d_in[1];
  const float* w_proj = (const float*)d_in[2];
  float* out = (float*)d_out;

  char* ws = (char*)d_ws;
  // bf16 scratch layout (all 16B-aligned offsets)
  short* xb  = (short*)(ws);                                    // 4096*768*2 = 6291456 B
  short* wab = (short*)(ws + 6291456);                          // 2304*768*2 = 3538944 B
  short* wpb = (short*)(ws + 6291456 + 3538944);                // 768*768*2  = 1179648 B
  short* qkv = (short*)(ws + 6291456 + 3538944 + 1179648);      // 4096*2304*2 = 18874368 B
  short* yb  = (short*)(ws + 6291456 + 3538944 + 1179648 + 18874368);  // 6291456 B

  // x -> bf16
  conv_bf16_kernel<<<3072, 256, 0, stream>>>(x, xb, 786432);
  // w_attn [768][2304] -> wab [2304][768] (B^T layout, bf16)
  transpose_bf16_kernel<<<dim3(QKV_N / 32, C_DIM / 32), 256, 0, stream>>>(w_attn, wab, C_DIM, QKV_N);
  // w_proj [768][768] -> wpb [768][768]^T
  transpose_bf16_kernel<<<dim3(C_DIM / 32, C_DIM / 32), 256, 0, stream>>>(w_proj, wpb, C_DIM, C_DIM);

  // qkv = x @ w_attn   (bf16 out)
  gemm_bf16<true><<<dim3(T_SEQ / 128, QKV_N / 128), 256, 0, stream>>>(xb, wab, (void*)qkv, T_SEQ, QKV_N, C_DIM);
  // attention
  attn_kernel<<<dim3(T_SEQ / 64, NH), 256, 0, stream>>>(qkv, yb);
  // out = y @ w_proj   (f32 out)
  gemm_bf16<false><<<dim3(T_SEQ / 128, C_DIM / 128), 256, 0, stream>>>(yb, wpb, (void*)out, T_SEQ, C_DIM, C_DIM);
}

// Round 3
// 202.416 us; speedup vs baseline: 1.5875x; 1.5875x over previous
//
#include <hip/hip_runtime.h>
#include <hip/hip_bf16.h>

typedef __attribute__((ext_vector_type(8))) short bfx8;
typedef __attribute__((ext_vector_type(4))) short bfx4;
typedef __attribute__((ext_vector_type(4))) float f32x4;
typedef __attribute__((ext_vector_type(4))) unsigned int u32x4;

#define T_SEQ 4096
#define C_DIM 768
#define NH    12
#define HD    64
#define QKV_N 2304

#define MFMA16(a, b, c) __builtin_amdgcn_mfma_f32_16x16x32_bf16((a), (b), (c), 0, 0, 0)

__device__ __forceinline__ short f2bf(float f) {
  __hip_bfloat16 h = __float2bfloat16(f);
  return __builtin_bit_cast(short, h);
}

__device__ __forceinline__ unsigned pack_bf2(float a, float b) {
  unsigned lo = (unsigned short)f2bf(a);
  unsigned hi = (unsigned short)f2bf(b);
  return (hi << 16) | lo;
}

// ---------------- f32 -> bf16 convert (vectorized) ----------------
__global__ __launch_bounds__(256) void conv_bf16_kernel(
    const float* __restrict__ in, short* __restrict__ out, int n4) {
  int i = blockIdx.x * 256 + threadIdx.x;
  if (i >= n4) return;
  float4 v = ((const float4*)in)[i];
  bfx4 o;
  o[0] = f2bf(v.x); o[1] = f2bf(v.y); o[2] = f2bf(v.z); o[3] = f2bf(v.w);
  ((bfx4*)out)[i] = o;
}

// ------------- f32 [R][Cc] -> bf16 transposed [Cc][R] -------------
__global__ __launch_bounds__(256) void transpose_bf16_kernel(
    const float* __restrict__ in, short* __restrict__ out, int R, int Cc) {
  __shared__ short tile[32][33];
  int bx = blockIdx.x * 32, by = blockIdx.y * 32;
  int tx = threadIdx.x & 31, ty = threadIdx.x >> 5;  // 32x8
#pragma unroll
  for (int i = 0; i < 32; i += 8)
    tile[ty + i][tx] = f2bf(in[(size_t)(by + ty + i) * Cc + (bx + tx)]);
  __syncthreads();
#pragma unroll
  for (int i = 0; i < 32; i += 8)
    out[(size_t)(bx + ty + i) * R + (by + tx)] = tile[tx][ty + i];
}

// ------------- bf16 V-transpose: qkv V block [T][768] -> Vt [768][T] -------------
__global__ __launch_bounds__(256) void transpose_v_kernel(
    const short* __restrict__ qkv, short* __restrict__ Vt) {
  __shared__ short tile[32][33];
  int t0 = blockIdx.x * 32, c0 = blockIdx.y * 32;
  int tx = threadIdx.x & 31, ty = threadIdx.x >> 5;
#pragma unroll
  for (int i = 0; i < 32; i += 8)
    tile[ty + i][tx] = qkv[(size_t)(t0 + ty + i) * QKV_N + 2 * C_DIM + c0 + tx];
  __syncthreads();
#pragma unroll
  for (int i = 0; i < 32; i += 8)
    Vt[(size_t)(c0 + ty + i) * T_SEQ + t0 + tx] = tile[tx][ty + i];
}

// ---------------- bf16 GEMM: C[M][N] = A[M][K] * Bt[N][K]^T ----------------
template <bool OUT_BF16>
__global__ __launch_bounds__(256) void gemm_bf16(
    const short* __restrict__ A, const short* __restrict__ Bt,
    void* __restrict__ C, int M, int N, int K) {
  __shared__ short As[128 * 32];
  __shared__ short Bs[128 * 32];
  const int tid  = threadIdx.x;
  const int lane = tid & 63;
  const int wave = tid >> 6;
  const int am0 = blockIdx.x * 128;
  const int bn0 = blockIdx.y * 128;
  const int wr = (wave >> 1) * 64;
  const int wc = (wave & 1) * 64;

  const f32x4 zero = {0.f, 0.f, 0.f, 0.f};
  f32x4 acc[4][4];
#pragma unroll
  for (int i = 0; i < 4; i++)
#pragma unroll
    for (int j = 0; j < 4; j++) acc[i][j] = zero;

  for (int k0 = 0; k0 < K; k0 += 32) {
#pragma unroll
    for (int i = 0; i < 2; i++) {
      int idx = i * 256 + tid;
      int r = idx >> 2;
      int c = (idx & 3) * 8;
      __builtin_amdgcn_global_load_lds(
          (const __attribute__((address_space(1))) void*)(A + (size_t)(am0 + r) * K + k0 + c),
          (__attribute__((address_space(3))) void*)(As + idx * 8), 16, 0, 0);
      __builtin_amdgcn_global_load_lds(
          (const __attribute__((address_space(1))) void*)(Bt + (size_t)(bn0 + r) * K + k0 + c),
          (__attribute__((address_space(3))) void*)(Bs + idx * 8), 16, 0, 0);
    }
    __syncthreads();

    bfx8 a[4], b[4];
#pragma unroll
    for (int mf = 0; mf < 4; mf++)
      a[mf] = *(const bfx8*)&As[(wr + mf * 16 + (lane & 15)) * 32 + (lane >> 4) * 8];
#pragma unroll
    for (int nf = 0; nf < 4; nf++)
      b[nf] = *(const bfx8*)&Bs[(wc + nf * 16 + (lane & 15)) * 32 + (lane >> 4) * 8];
#pragma unroll
    for (int mf = 0; mf < 4; mf++)
#pragma unroll
      for (int nf = 0; nf < 4; nf++)
        acc[mf][nf] = MFMA16(a[mf], b[nf], acc[mf][nf]);
    __syncthreads();
  }

#pragma unroll
  for (int mf = 0; mf < 4; mf++) {
#pragma unroll
    for (int r = 0; r < 4; r++) {
      int row = am0 + wr + mf * 16 + (lane >> 4) * 4 + r;
#pragma unroll
      for (int nf = 0; nf < 4; nf++) {
        int col = bn0 + wc + nf * 16 + (lane & 15);
        float v = acc[mf][nf][r];
        if (OUT_BF16)
          ((short*)C)[(size_t)row * N + col] = f2bf(v);
        else
          ((float*)C)[(size_t)row * N + col] = v;
      }
    }
  }
}

// ---------------- causal flash attention ----------------
// 4 waves/block, 32 q-rows/wave (2 q-subtiles of 16), KVBLK=64.
// K-tile [64 keys][64 d] and Vt-tile [64 d][64 keys] staged in LDS,
// slot-XOR swizzled (slot ^= row&7) via pre-swizzled global source (rule #21).
// Swapped QK^T: S^T = mfma(K, Q); P redistributed to PV B-frag via 8 shfl
// per 32-key group (proven in round 2).
__global__ __launch_bounds__(256) void attn_kernel(
    const short* __restrict__ qkv, const short* __restrict__ Vt,
    short* __restrict__ yb) {
  __shared__ short Ks[64 * 64];
  __shared__ short Vs[64 * 64];

  const int tid  = threadIdx.x;
  const int lane = tid & 63;
  const int wv   = tid >> 6;
  const int col  = lane & 15;
  const int g    = lane >> 4;

  // heavy-first ordering: q_rank 0 = largest q0, heads interleaved
  const int bid    = blockIdx.x;
  const int h      = bid % NH;
  const int q_idx  = (T_SEQ / 128 - 1) - bid / NH;
  const int q0     = q_idx * 128;
  const int qw     = q0 + wv * 32;  // this wave's first q row

  const int hq = h * HD;
  const int hk = C_DIM + h * HD;
  const short* Vth = Vt + (size_t)h * HD * T_SEQ;

  // Q fragments: qf[qq][hf] = Q[qw+qq*16+col][hf*32 + g*8 + j]
  bfx8 qf[2][2];
#pragma unroll
  for (int qq = 0; qq < 2; qq++)
#pragma unroll
    for (int hf = 0; hf < 2; hf++)
      qf[qq][hf] = *(const bfx8*)&qkv[(size_t)(qw + qq * 16 + col) * QKV_N + hq + hf * 32 + g * 8];

  const f32x4 zero = {0.f, 0.f, 0.f, 0.f};
  f32x4 o[2][4];
#pragma unroll
  for (int qq = 0; qq < 2; qq++)
#pragma unroll
    for (int c = 0; c < 4; c++) o[qq][c] = zero;
  float m[2] = {-INFINITY, -INFINITY};
  float lsum[2] = {0.f, 0.f};

  const int src0 = (g & 1) * 32 + col;
  const int src1 = src0 + 16;
  const int nt = (q0 + 128) / 64;

  for (int t = 0; t < nt; t++) {
    const int kv = t * 64;
    // ---- stage K and V^T tiles (linear LDS dest, swizzled global src) ----
#pragma unroll
    for (int i = 0; i < 2; i++) {
      int idx = i * 256 + tid;       // 0..511 -> 16B slot
      int row = idx >> 3;            // 0..63
      int slot = idx & 7;
      int ss = slot ^ (row & 7);
      __builtin_amdgcn_global_load_lds(
          (const __attribute__((address_space(1))) void*)(qkv + (size_t)(kv + row) * QKV_N + hk + ss * 8),
          (__attribute__((address_space(3))) void*)(Ks + idx * 8), 16, 0, 0);
      __builtin_amdgcn_global_load_lds(
          (const __attribute__((address_space(1))) void*)(Vth + (size_t)row * T_SEQ + kv + ss * 8),
          (__attribute__((address_space(3))) void*)(Vs + idx * 8), 16, 0, 0);
    }
    __syncthreads();

    if (kv <= qw + 31) {  // wave-uniform: skip fully-masked tiles
      // ---- K A-frags: kf[sub][hf], row = sub*16+col (key), k = d ----
      bfx8 kf[4][2];
#pragma unroll
      for (int sub = 0; sub < 4; sub++) {
        int row = sub * 16 + col;
#pragma unroll
        for (int hf = 0; hf < 2; hf++)
          kf[sub][hf] = *(const bfx8*)&Ks[row * 64 + (((hf << 2) | g) ^ (row & 7)) * 8];
      }
      // ---- V^T A-frags: vtf[ks][c], row = c*16+col (d), k = key ----
      bfx8 vtf[2][4];
#pragma unroll
      for (int ks = 0; ks < 2; ks++) {
#pragma unroll
        for (int c = 0; c < 4; c++) {
          int row = c * 16 + col;
          vtf[ks][c] = *(const bfx8*)&Vs[row * 64 + (((ks << 2) | g) ^ (row & 7)) * 8];
        }
      }

#pragma unroll
      for (int qq = 0; qq < 2; qq++) {
        const int qabs = qw + qq * 16 + col;
        // ---- QK^T: s[sub][r] = S^T[key=kv+sub*16+4g+r][q] ----
        f32x4 s[4];
#pragma unroll
        for (int sub = 0; sub < 4; sub++) {
          s[sub] = zero;
          s[sub] = MFMA16(kf[sub][0], qf[qq][0], s[sub]);
          s[sub] = MFMA16(kf[sub][1], qf[qq][1], s[sub]);
        }
        // ---- mask + scale + online softmax ----
        float sv[4][4];
        float tm = -INFINITY;
#pragma unroll
        for (int sub = 0; sub < 4; sub++)
#pragma unroll
          for (int r = 0; r < 4; r++) {
            int key = kv + sub * 16 + 4 * g + r;
            sv[sub][r] = (key > qabs) ? -INFINITY : s[sub][r] * 0.125f;
            tm = fmaxf(tm, sv[sub][r]);
          }
        tm = fmaxf(tm, __shfl_xor(tm, 16));
        tm = fmaxf(tm, __shfl_xor(tm, 32));
        float mnew = fmaxf(m[qq], tm);
        float scale_old = __expf(m[qq] - mnew);

        float p[4][4], psum = 0.f;
#pragma unroll
        for (int sub = 0; sub < 4; sub++)
#pragma unroll
          for (int r = 0; r < 4; r++) {
            p[sub][r] = __expf(sv[sub][r] - mnew);
            psum += p[sub][r];
          }
        psum += __shfl_xor(psum, 16);
        psum += __shfl_xor(psum, 32);
        lsum[qq] = lsum[qq] * scale_old + psum;
        m[qq] = mnew;

#pragma unroll
        for (int c = 0; c < 4; c++)
#pragma unroll
          for (int r = 0; r < 4; r++) o[qq][c][r] *= scale_old;

        // ---- PV per 32-key step: redistribute P then 4 MFMA ----
#pragma unroll
        for (int ks = 0; ks < 2; ks++) {
          unsigned L0 = pack_bf2(p[2 * ks][0], p[2 * ks][1]);
          unsigned L1 = pack_bf2(p[2 * ks][2], p[2 * ks][3]);
          unsigned H0 = pack_bf2(p[2 * ks + 1][0], p[2 * ks + 1][1]);
          unsigned H1 = pack_bf2(p[2 * ks + 1][2], p[2 * ks + 1][3]);
          unsigned a0 = __shfl(L0, src0, 64), b0 = __shfl(H0, src0, 64);
          unsigned a1 = __shfl(L1, src0, 64), b1 = __shfl(H1, src0, 64);
          unsigned a2 = __shfl(L0, src1, 64), b2 = __shfl(H0, src1, 64);
          unsigned a3 = __shfl(L1, src1, 64), b3 = __shfl(H1, src1, 64);
          u32x4 w;
          w[0] = (g < 2) ? a0 : b0;
          w[1] = (g < 2) ? a1 : b1;
          w[2] = (g < 2) ? a2 : b2;
          w[3] = (g < 2) ? a3 : b3;
          bfx8 pf = __builtin_bit_cast(bfx8, w);
#pragma unroll
          for (int c = 0; c < 4; c++)
            o[qq][c] = MFMA16(vtf[ks][c], pf, o[qq][c]);
        }
      }
    }
    __syncthreads();
  }

#pragma unroll
  for (int qq = 0; qq < 2; qq++) {
    float inv = 1.f / lsum[qq];
#pragma unroll
    for (int c = 0; c < 4; c++) {
      bfx4 ov;
#pragma unroll
      for (int r = 0; r < 4; r++) ov[r] = f2bf(o[qq][c][r] * inv);
      *(bfx4*)&yb[(size_t)(qw + qq * 16 + col) * C_DIM + h * HD + c * 16 + g * 4] = ov;
    }
  }
}

// ---------------- launch ----------------
extern "C" void kernel_launch(void* const* d_in, const int* in_sizes, int n_in,
                              void* d_out, int out_size, void* d_ws, size_t ws_size,
                              hipStream_t stream) {
  const float* x      = (const float*)d_in[0];
  const float* w_attn = (const float*)d_in[1];
  const float* w_proj = (const float*)d_in[2];
  float* out = (float*)d_out;

  char* ws = (char*)d_ws;
  short* xb  = (short*)(ws);                                    // 6291456 B (xb; reused as Vt)
  short* wab = (short*)(ws + 6291456);                          // 3538944 B
  short* wpb = (short*)(ws + 6291456 + 3538944);                // 1179648 B
  short* qkv = (short*)(ws + 6291456 + 3538944 + 1179648);      // 18874368 B
  short* yb  = (short*)(ws + 6291456 + 3538944 + 1179648 + 18874368);  // 6291456 B
  short* Vt  = xb;  // xb is dead after the QKV GEMM; Vt is 768*4096*2 = 6291456 B

  conv_bf16_kernel<<<3072, 256, 0, stream>>>(x, xb, 786432);
  transpose_bf16_kernel<<<dim3(QKV_N / 32, C_DIM / 32), 256, 0, stream>>>(w_attn, wab, C_DIM, QKV_N);
  transpose_bf16_kernel<<<dim3(C_DIM / 32, C_DIM / 32), 256, 0, stream>>>(w_proj, wpb, C_DIM, C_DIM);

  gemm_bf16<true><<<dim3(T_SEQ / 128, QKV_N / 128), 256, 0, stream>>>(xb, wab, (void*)qkv, T_SEQ, QKV_N, C_DIM);
  // V^T for attention PV (overwrites xb — dead now)
  transpose_v_kernel<<<dim3(T_SEQ / 32, C_DIM / 32), 256, 0, stream>>>(qkv, Vt);
  attn_kernel<<<(T_SEQ / 128) * NH, 256, 0, stream>>>(qkv, Vt, yb);
  gemm_bf16<false><<<dim3(T_SEQ / 128, C_DIM / 128), 256, 0, stream>>>(yb, wpb, (void*)out, T_SEQ, C_DIM, C_DIM);
}

// Round 4
// 162.744 us; speedup vs baseline: 1.9744x; 1.2438x over previous
//
#include <hip/hip_runtime.h>
#include <hip/hip_bf16.h>

typedef __attribute__((ext_vector_type(8))) short bfx8;
typedef __attribute__((ext_vector_type(4))) short bfx4;
typedef __attribute__((ext_vector_type(4))) float f32x4;
typedef __attribute__((ext_vector_type(4))) unsigned int u32x4;

#define T_SEQ 4096
#define C_DIM 768
#define NH    12
#define HD    64
#define QKV_N 2304

#define MFMA16(a, b, c) __builtin_amdgcn_mfma_f32_16x16x32_bf16((a), (b), (c), 0, 0, 0)

__device__ __forceinline__ short f2bf(float f) {
  __hip_bfloat16 h = __float2bfloat16(f);
  return __builtin_bit_cast(short, h);
}

__device__ __forceinline__ unsigned pack_bf2(float a, float b) {
  unsigned lo = (unsigned short)f2bf(a);
  unsigned hi = (unsigned short)f2bf(b);
  return (hi << 16) | lo;
}

// ---------------- f32 -> bf16 convert (vectorized) ----------------
__global__ __launch_bounds__(256) void conv_bf16_kernel(
    const float* __restrict__ in, short* __restrict__ out, int n4) {
  int i = blockIdx.x * 256 + threadIdx.x;
  if (i >= n4) return;
  float4 v = ((const float4*)in)[i];
  bfx4 o;
  o[0] = f2bf(v.x); o[1] = f2bf(v.y); o[2] = f2bf(v.z); o[3] = f2bf(v.w);
  ((bfx4*)out)[i] = o;
}

// ------------- f32 [R][Cc] -> bf16 transposed [Cc][R] -------------
__global__ __launch_bounds__(256) void transpose_bf16_kernel(
    const float* __restrict__ in, short* __restrict__ out, int R, int Cc) {
  __shared__ short tile[32][33];
  int bx = blockIdx.x * 32, by = blockIdx.y * 32;
  int tx = threadIdx.x & 31, ty = threadIdx.x >> 5;  // 32x8
#pragma unroll
  for (int i = 0; i < 32; i += 8)
    tile[ty + i][tx] = f2bf(in[(size_t)(by + ty + i) * Cc + (bx + tx)]);
  __syncthreads();
#pragma unroll
  for (int i = 0; i < 32; i += 8)
    out[(size_t)(bx + ty + i) * R + (by + tx)] = tile[tx][ty + i];
}

// ------------- bf16 V-transpose: qkv V block [T][768] -> Vt [768][T] -------------
__global__ __launch_bounds__(256) void transpose_v_kernel(
    const short* __restrict__ qkv, short* __restrict__ Vt) {
  __shared__ short tile[32][33];
  int t0 = blockIdx.x * 32, c0 = blockIdx.y * 32;
  int tx = threadIdx.x & 31, ty = threadIdx.x >> 5;
#pragma unroll
  for (int i = 0; i < 32; i += 8)
    tile[ty + i][tx] = qkv[(size_t)(t0 + ty + i) * QKV_N + 2 * C_DIM + c0 + tx];
  __syncthreads();
#pragma unroll
  for (int i = 0; i < 32; i += 8)
    Vt[(size_t)(c0 + ty + i) * T_SEQ + t0 + tx] = tile[tx][ty + i];
}

// ---------------- bf16 GEMM: C[M][N] = A[M][K] * Bt[N][K]^T ----------------
template <bool OUT_BF16>
__global__ __launch_bounds__(256) void gemm_bf16(
    const short* __restrict__ A, const short* __restrict__ Bt,
    void* __restrict__ C, int M, int N, int K) {
  __shared__ short As[128 * 32];
  __shared__ short Bs[128 * 32];
  const int tid  = threadIdx.x;
  const int lane = tid & 63;
  const int wave = tid >> 6;
  const int am0 = blockIdx.x * 128;
  const int bn0 = blockIdx.y * 128;
  const int wr = (wave >> 1) * 64;
  const int wc = (wave & 1) * 64;

  const f32x4 zero = {0.f, 0.f, 0.f, 0.f};
  f32x4 acc[4][4];
#pragma unroll
  for (int i = 0; i < 4; i++)
#pragma unroll
    for (int j = 0; j < 4; j++) acc[i][j] = zero;

  for (int k0 = 0; k0 < K; k0 += 32) {
#pragma unroll
    for (int i = 0; i < 2; i++) {
      int idx = i * 256 + tid;
      int r = idx >> 2;
      int c = (idx & 3) * 8;
      __builtin_amdgcn_global_load_lds(
          (const __attribute__((address_space(1))) void*)(A + (size_t)(am0 + r) * K + k0 + c),
          (__attribute__((address_space(3))) void*)(As + idx * 8), 16, 0, 0);
      __builtin_amdgcn_global_load_lds(
          (const __attribute__((address_space(1))) void*)(Bt + (size_t)(bn0 + r) * K + k0 + c),
          (__attribute__((address_space(3))) void*)(Bs + idx * 8), 16, 0, 0);
    }
    __syncthreads();

    bfx8 a[4], b[4];
#pragma unroll
    for (int mf = 0; mf < 4; mf++)
      a[mf] = *(const bfx8*)&As[(wr + mf * 16 + (lane & 15)) * 32 + (lane >> 4) * 8];
#pragma unroll
    for (int nf = 0; nf < 4; nf++)
      b[nf] = *(const bfx8*)&Bs[(wc + nf * 16 + (lane & 15)) * 32 + (lane >> 4) * 8];
#pragma unroll
    for (int mf = 0; mf < 4; mf++)
#pragma unroll
      for (int nf = 0; nf < 4; nf++)
        acc[mf][nf] = MFMA16(a[mf], b[nf], acc[mf][nf]);
    __syncthreads();
  }

#pragma unroll
  for (int mf = 0; mf < 4; mf++) {
#pragma unroll
    for (int r = 0; r < 4; r++) {
      int row = am0 + wr + mf * 16 + (lane >> 4) * 4 + r;
#pragma unroll
      for (int nf = 0; nf < 4; nf++) {
        int col = bn0 + wc + nf * 16 + (lane & 15);
        float v = acc[mf][nf][r];
        if (OUT_BF16)
          ((short*)C)[(size_t)row * N + col] = f2bf(v);
        else
          ((float*)C)[(size_t)row * N + col] = v;
      }
    }
  }
}

// ---------------- causal flash attention ----------------
// 4 waves/block, 16 q-rows/wave (64 q/block), KVBLK=64, grid=768 (3 waves/SIMD).
// K-tile [64 keys][64 d] and Vt-tile [64 d][64 keys] double-buffered in LDS,
// slot-XOR swizzled (slot ^= row&7) via pre-swizzled global source (rule #21).
// Counted-vmcnt prefetch: issue tile t+1's 4 loads, wait vmcnt(4) (tile t's
// FIFO-oldest 4 done), raw s_barrier; trailing __syncthreads protects reuse.
__global__ __launch_bounds__(256) void attn_kernel(
    const short* __restrict__ qkv, const short* __restrict__ Vt,
    short* __restrict__ yb) {
  __shared__ short Ks[2][64 * 64];
  __shared__ short Vs[2][64 * 64];

  const int tid  = threadIdx.x;
  const int lane = tid & 63;
  const int wv   = tid >> 6;
  const int col  = lane & 15;
  const int g    = lane >> 4;

  // heavy-first ordering: largest q first, heads interleaved
  const int bid   = blockIdx.x;
  const int h     = bid % NH;
  const int q_idx = (T_SEQ / 64 - 1) - bid / NH;
  const int q0    = q_idx * 64;
  const int qw    = q0 + wv * 16;  // this wave's 16 q rows

  const int hq = h * HD;
  const int hk = C_DIM + h * HD;
  const short* Vth = Vt + (size_t)h * HD * T_SEQ;

  // staging addresses (same for every tile except kv offset)
  const int sidx0 = tid;          // two 16B slots per thread per tensor
  const int sidx1 = 256 + tid;
  const int srow0 = sidx0 >> 3, sslot0 = (sidx0 & 7) ^ (srow0 & 7);
  const int srow1 = sidx1 >> 3, sslot1 = (sidx1 & 7) ^ (srow1 & 7);

#define STAGE(buf, kvoff)                                                               \
  do {                                                                                  \
    __builtin_amdgcn_global_load_lds(                                                   \
        (const __attribute__((address_space(1))) void*)(qkv + (size_t)((kvoff) + srow0) * QKV_N + hk + sslot0 * 8), \
        (__attribute__((address_space(3))) void*)(&Ks[buf][sidx0 * 8]), 16, 0, 0);      \
    __builtin_amdgcn_global_load_lds(                                                   \
        (const __attribute__((address_space(1))) void*)(qkv + (size_t)((kvoff) + srow1) * QKV_N + hk + sslot1 * 8), \
        (__attribute__((address_space(3))) void*)(&Ks[buf][sidx1 * 8]), 16, 0, 0);      \
    __builtin_amdgcn_global_load_lds(                                                   \
        (const __attribute__((address_space(1))) void*)(Vth + (size_t)srow0 * T_SEQ + (kvoff) + sslot0 * 8), \
        (__attribute__((address_space(3))) void*)(&Vs[buf][sidx0 * 8]), 16, 0, 0);      \
    __builtin_amdgcn_global_load_lds(                                                   \
        (const __attribute__((address_space(1))) void*)(Vth + (size_t)srow1 * T_SEQ + (kvoff) + sslot1 * 8), \
        (__attribute__((address_space(3))) void*)(&Vs[buf][sidx1 * 8]), 16, 0, 0);      \
  } while (0)

  // Q fragments: qf[hf] = Q[qw+col][hf*32 + g*8 + j]
  bfx8 qf[2];
#pragma unroll
  for (int hf = 0; hf < 2; hf++)
    qf[hf] = *(const bfx8*)&qkv[(size_t)(qw + col) * QKV_N + hq + hf * 32 + g * 8];

  const f32x4 zero = {0.f, 0.f, 0.f, 0.f};
  f32x4 o[4];
#pragma unroll
  for (int c = 0; c < 4; c++) o[c] = zero;
  float m = -INFINITY, lsum = 0.f;

  const int qabs = qw + col;
  const int src0 = (g & 1) * 32 + col;
  const int src1 = src0 + 16;
  const int nt = q_idx + 1;

  STAGE(0, 0);

  for (int t = 0; t < nt; t++) {
    const int cur = t & 1;
    const int kv = t * 64;
    if (t + 1 < nt) {
      STAGE(cur ^ 1, kv + 64);
      asm volatile("s_waitcnt vmcnt(4)" ::: "memory");
    } else {
      asm volatile("s_waitcnt vmcnt(0)" ::: "memory");
    }
    __builtin_amdgcn_s_barrier();

    if (kv <= qw + 15) {  // wave-uniform: skip fully-masked tiles
      // K A-frags: kf[sub][hf], row = sub*16+col (key), k = d
      bfx8 kf[4][2];
#pragma unroll
      for (int sub = 0; sub < 4; sub++) {
        int row = sub * 16 + col;
#pragma unroll
        for (int hf = 0; hf < 2; hf++)
          kf[sub][hf] = *(const bfx8*)&Ks[cur][row * 64 + (((hf << 2) | g) ^ (row & 7)) * 8];
      }

      // QK^T: s[sub][r] = S^T[key=kv+sub*16+4g+r][q=col]
      f32x4 s[4];
#pragma unroll
      for (int sub = 0; sub < 4; sub++) {
        s[sub] = zero;
        s[sub] = MFMA16(kf[sub][0], qf[0], s[sub]);
        s[sub] = MFMA16(kf[sub][1], qf[1], s[sub]);
      }

      float sv[4][4];
      float tm = -INFINITY;
      if (kv + 63 <= qw) {  // fully unmasked fast path (wave-uniform)
#pragma unroll
        for (int sub = 0; sub < 4; sub++)
#pragma unroll
          for (int r = 0; r < 4; r++) {
            sv[sub][r] = s[sub][r] * 0.125f;
            tm = fmaxf(tm, sv[sub][r]);
          }
      } else {
#pragma unroll
        for (int sub = 0; sub < 4; sub++)
#pragma unroll
          for (int r = 0; r < 4; r++) {
            int key = kv + sub * 16 + 4 * g + r;
            sv[sub][r] = (key > qabs) ? -INFINITY : s[sub][r] * 0.125f;
            tm = fmaxf(tm, sv[sub][r]);
          }
      }
      tm = fmaxf(tm, __shfl_xor(tm, 16));
      tm = fmaxf(tm, __shfl_xor(tm, 32));
      float mnew = fmaxf(m, tm);
      float scale_old = __expf(m - mnew);

      float p[4][4], psum = 0.f;
#pragma unroll
      for (int sub = 0; sub < 4; sub++)
#pragma unroll
        for (int r = 0; r < 4; r++) {
          p[sub][r] = __expf(sv[sub][r] - mnew);
          psum += p[sub][r];
        }
      psum += __shfl_xor(psum, 16);
      psum += __shfl_xor(psum, 32);
      lsum = lsum * scale_old + psum;
      m = mnew;

#pragma unroll
      for (int c = 0; c < 4; c++)
#pragma unroll
        for (int r = 0; r < 4; r++) o[c][r] *= scale_old;

      // V^T A-frags + PV per 32-key step
#pragma unroll
      for (int ks = 0; ks < 2; ks++) {
        unsigned L0 = pack_bf2(p[2 * ks][0], p[2 * ks][1]);
        unsigned L1 = pack_bf2(p[2 * ks][2], p[2 * ks][3]);
        unsigned H0 = pack_bf2(p[2 * ks + 1][0], p[2 * ks + 1][1]);
        unsigned H1 = pack_bf2(p[2 * ks + 1][2], p[2 * ks + 1][3]);
        unsigned a0 = __shfl(L0, src0, 64), b0 = __shfl(H0, src0, 64);
        unsigned a1 = __shfl(L1, src0, 64), b1 = __shfl(H1, src0, 64);
        unsigned a2 = __shfl(L0, src1, 64), b2 = __shfl(H0, src1, 64);
        unsigned a3 = __shfl(L1, src1, 64), b3 = __shfl(H1, src1, 64);
        u32x4 w;
        w[0] = (g < 2) ? a0 : b0;
        w[1] = (g < 2) ? a1 : b1;
        w[2] = (g < 2) ? a2 : b2;
        w[3] = (g < 2) ? a3 : b3;
        bfx8 pf = __builtin_bit_cast(bfx8, w);
#pragma unroll
        for (int c = 0; c < 4; c++) {
          int row = c * 16 + col;
          bfx8 vtf = *(const bfx8*)&Vs[cur][row * 64 + (((ks << 2) | g) ^ (row & 7)) * 8];
          o[c] = MFMA16(vtf, pf, o[c]);
        }
      }
    }
    __syncthreads();  // reads of buf cur done before next iter restages it
  }

  float inv = 1.f / lsum;
#pragma unroll
  for (int c = 0; c < 4; c++) {
    bfx4 ov;
#pragma unroll
    for (int r = 0; r < 4; r++) ov[r] = f2bf(o[c][r] * inv);
    *(bfx4*)&yb[(size_t)(qw + col) * C_DIM + h * HD + c * 16 + g * 4] = ov;
  }
#undef STAGE
}

// ---------------- launch ----------------
extern "C" void kernel_launch(void* const* d_in, const int* in_sizes, int n_in,
                              void* d_out, int out_size, void* d_ws, size_t ws_size,
                              hipStream_t stream) {
  const float* x      = (const float*)d_in[0];
  const float* w_attn = (const float*)d_in[1];
  const float* w_proj = (const float*)d_in[2];
  float* out = (float*)d_out;

  char* ws = (char*)d_ws;
  short* xb  = (short*)(ws);                                    // 6291456 B (reused as Vt)
  short* wab = (short*)(ws + 6291456);                          // 3538944 B
  short* wpb = (short*)(ws + 6291456 + 3538944);                // 1179648 B
  short* qkv = (short*)(ws + 6291456 + 3538944 + 1179648);      // 18874368 B
  short* yb  = (short*)(ws + 6291456 + 3538944 + 1179648 + 18874368);  // 6291456 B
  short* Vt  = xb;  // xb dead after QKV GEMM; Vt = 768*4096*2 B

  conv_bf16_kernel<<<3072, 256, 0, stream>>>(x, xb, 786432);
  transpose_bf16_kernel<<<dim3(QKV_N / 32, C_DIM / 32), 256, 0, stream>>>(w_attn, wab, C_DIM, QKV_N);
  transpose_bf16_kernel<<<dim3(C_DIM / 32, C_DIM / 32), 256, 0, stream>>>(w_proj, wpb, C_DIM, C_DIM);

  gemm_bf16<true><<<dim3(T_SEQ / 128, QKV_N / 128), 256, 0, stream>>>(xb, wab, (void*)qkv, T_SEQ, QKV_N, C_DIM);
  transpose_v_kernel<<<dim3(T_SEQ / 32, C_DIM / 32), 256, 0, stream>>>(qkv, Vt);
  attn_kernel<<<(T_SEQ / 64) * NH, 256, 0, stream>>>(qkv, Vt, yb);
  gemm_bf16<false><<<dim3(T_SEQ / 128, C_DIM / 128), 256, 0, stream>>>(yb, wpb, (void*)out, T_SEQ, C_DIM, C_DIM);
}

// Round 5
// 159.320 us; speedup vs baseline: 2.0169x; 1.0215x over previous
//
#include <hip/hip_runtime.h>
#include <hip/hip_bf16.h>

typedef __attribute__((ext_vector_type(8))) short bfx8;
typedef __attribute__((ext_vector_type(4))) short bfx4;
typedef __attribute__((ext_vector_type(4))) float f32x4;
typedef __attribute__((ext_vector_type(4))) unsigned int u32x4;

#define T_SEQ 4096
#define C_DIM 768
#define NH    12
#define HD    64
#define QKV_N 2304

#define MFMA16(a, b, c) __builtin_amdgcn_mfma_f32_16x16x32_bf16((a), (b), (c), 0, 0, 0)

__device__ __forceinline__ short f2bf(float f) {
  __hip_bfloat16 h = __float2bfloat16(f);
  return __builtin_bit_cast(short, h);
}

// ---------------- f32 -> bf16 convert (vectorized) ----------------
__global__ __launch_bounds__(256) void conv_bf16_kernel(
    const float* __restrict__ in, short* __restrict__ out, int n4) {
  int i = blockIdx.x * 256 + threadIdx.x;
  if (i >= n4) return;
  float4 v = ((const float4*)in)[i];
  bfx4 o;
  o[0] = f2bf(v.x); o[1] = f2bf(v.y); o[2] = f2bf(v.z); o[3] = f2bf(v.w);
  ((bfx4*)out)[i] = o;
}

// ------------- f32 [R][Cc] -> bf16 transposed [Cc][R], first qcols columns scaled -------------
__global__ __launch_bounds__(256) void transpose_bf16_kernel(
    const float* __restrict__ in, short* __restrict__ out, int R, int Cc,
    int qcols, float qscale) {
  __shared__ short tile[32][33];
  int bx = blockIdx.x * 32, by = blockIdx.y * 32;
  int tx = threadIdx.x & 31, ty = threadIdx.x >> 5;  // 32x8
  float sc = (bx + tx) < qcols ? qscale : 1.0f;
#pragma unroll
  for (int i = 0; i < 32; i += 8)
    tile[ty + i][tx] = f2bf(in[(size_t)(by + ty + i) * Cc + (bx + tx)] * sc);
  __syncthreads();
#pragma unroll
  for (int i = 0; i < 32; i += 8)
    out[(size_t)(bx + ty + i) * R + (by + tx)] = tile[tx][ty + i];
}

// ------------- bf16 V-transpose: qkv V block [T][768] -> Vt [768][T] -------------
__global__ __launch_bounds__(256) void transpose_v_kernel(
    const short* __restrict__ qkv, short* __restrict__ Vt) {
  __shared__ short tile[32][33];
  int t0 = blockIdx.x * 32, c0 = blockIdx.y * 32;
  int tx = threadIdx.x & 31, ty = threadIdx.x >> 5;
#pragma unroll
  for (int i = 0; i < 32; i += 8)
    tile[ty + i][tx] = qkv[(size_t)(t0 + ty + i) * QKV_N + 2 * C_DIM + c0 + tx];
  __syncthreads();
#pragma unroll
  for (int i = 0; i < 32; i += 8)
    Vt[(size_t)(c0 + ty + i) * T_SEQ + t0 + tx] = tile[tx][ty + i];
}

// ---------------- bf16 GEMM: C[M][N] = A[M][K] * Bt[N][K]^T ----------------
template <bool OUT_BF16>
__global__ __launch_bounds__(256) void gemm_bf16(
    const short* __restrict__ A, const short* __restrict__ Bt,
    void* __restrict__ C, int M, int N, int K) {
  __shared__ short As[128 * 32];
  __shared__ short Bs[128 * 32];
  const int tid  = threadIdx.x;
  const int lane = tid & 63;
  const int wave = tid >> 6;
  const int am0 = blockIdx.x * 128;
  const int bn0 = blockIdx.y * 128;
  const int wr = (wave >> 1) * 64;
  const int wc = (wave & 1) * 64;

  const f32x4 zero = {0.f, 0.f, 0.f, 0.f};
  f32x4 acc[4][4];
#pragma unroll
  for (int i = 0; i < 4; i++)
#pragma unroll
    for (int j = 0; j < 4; j++) acc[i][j] = zero;

  for (int k0 = 0; k0 < K; k0 += 32) {
#pragma unroll
    for (int i = 0; i < 2; i++) {
      int idx = i * 256 + tid;
      int r = idx >> 2;
      int c = (idx & 3) * 8;
      __builtin_amdgcn_global_load_lds(
          (const __attribute__((address_space(1))) void*)(A + (size_t)(am0 + r) * K + k0 + c),
          (__attribute__((address_space(3))) void*)(As + idx * 8), 16, 0, 0);
      __builtin_amdgcn_global_load_lds(
          (const __attribute__((address_space(1))) void*)(Bt + (size_t)(bn0 + r) * K + k0 + c),
          (__attribute__((address_space(3))) void*)(Bs + idx * 8), 16, 0, 0);
    }
    __syncthreads();

    bfx8 a[4], b[4];
#pragma unroll
    for (int mf = 0; mf < 4; mf++)
      a[mf] = *(const bfx8*)&As[(wr + mf * 16 + (lane & 15)) * 32 + (lane >> 4) * 8];
#pragma unroll
    for (int nf = 0; nf < 4; nf++)
      b[nf] = *(const bfx8*)&Bs[(wc + nf * 16 + (lane & 15)) * 32 + (lane >> 4) * 8];
#pragma unroll
    for (int mf = 0; mf < 4; mf++)
#pragma unroll
      for (int nf = 0; nf < 4; nf++)
        acc[mf][nf] = MFMA16(a[mf], b[nf], acc[mf][nf]);
    __syncthreads();
  }

#pragma unroll
  for (int mf = 0; mf < 4; mf++) {
#pragma unroll
    for (int r = 0; r < 4; r++) {
      int row = am0 + wr + mf * 16 + (lane >> 4) * 4 + r;
#pragma unroll
      for (int nf = 0; nf < 4; nf++) {
        int col = bn0 + wc + nf * 16 + (lane & 15);
        float v = acc[mf][nf][r];
        if (OUT_BF16)
          ((short*)C)[(size_t)row * N + col] = f2bf(v);
        else
          ((float*)C)[(size_t)row * N + col] = v;
      }
    }
  }
}

// ---------------- causal flash attention ----------------
// 4 waves/block; heavy/light q32-tile pairing: waves 0-1 own tile 127-p,
// waves 2-3 own tile p (mirror). Block stages kv tiles once for both.
// KVBLK=64, K/Vt tiles double-buffered in LDS with slot-XOR swizzle
// (linear dest + pre-swizzled global source, rule #21), counted-vmcnt prefetch.
// Q pre-scaled by 1/8 (folded into w_attn Q-columns). Softmax: defer-max
// (THR=5), P packed by truncation with psum from the same truncated values.
__global__ __launch_bounds__(256) void attn_kernel(
    const short* __restrict__ qkv, const short* __restrict__ Vt,
    short* __restrict__ yb) {
  __shared__ short Ks[2][64 * 64];
  __shared__ short Vs[2][64 * 64];

  const int tid  = threadIdx.x;
  const int lane = tid & 63;
  const int wv   = tid >> 6;
  const int col  = lane & 15;
  const int g    = lane >> 4;

  const int bid = blockIdx.x;
  const int h   = bid % NH;
  const int pr  = bid / NH;            // 0..63, 0 = heaviest pair
  const int myi = (wv < 2) ? (127 - pr) : pr;   // q32-tile index
  const int qw  = myi * 32 + (wv & 1) * 16;     // this wave's 16 q rows
  const int nt  = ((127 - pr) * 32 + 31) / 64 + 1;  // block tile count (heavy)

  const int hq = h * HD;
  const int hk = C_DIM + h * HD;
  const short* Vth = Vt + (size_t)h * HD * T_SEQ;

  const int sidx0 = tid;
  const int sidx1 = 256 + tid;
  const int srow0 = sidx0 >> 3, sslot0 = (sidx0 & 7) ^ (srow0 & 7);
  const int srow1 = sidx1 >> 3, sslot1 = (sidx1 & 7) ^ (srow1 & 7);

#define STAGE(buf, kvoff)                                                               \
  do {                                                                                  \
    __builtin_amdgcn_global_load_lds(                                                   \
        (const __attribute__((address_space(1))) void*)(qkv + (size_t)((kvoff) + srow0) * QKV_N + hk + sslot0 * 8), \
        (__attribute__((address_space(3))) void*)(&Ks[buf][sidx0 * 8]), 16, 0, 0);      \
    __builtin_amdgcn_global_load_lds(                                                   \
        (const __attribute__((address_space(1))) void*)(qkv + (size_t)((kvoff) + srow1) * QKV_N + hk + sslot1 * 8), \
        (__attribute__((address_space(3))) void*)(&Ks[buf][sidx1 * 8]), 16, 0, 0);      \
    __builtin_amdgcn_global_load_lds(                                                   \
        (const __attribute__((address_space(1))) void*)(Vth + (size_t)srow0 * T_SEQ + (kvoff) + sslot0 * 8), \
        (__attribute__((address_space(3))) void*)(&Vs[buf][sidx0 * 8]), 16, 0, 0);      \
    __builtin_amdgcn_global_load_lds(                                                   \
        (const __attribute__((address_space(1))) void*)(Vth + (size_t)srow1 * T_SEQ + (kvoff) + sslot1 * 8), \
        (__attribute__((address_space(3))) void*)(&Vs[buf][sidx1 * 8]), 16, 0, 0);      \
  } while (0)

  // Q fragments (pre-scaled by 1/8 in wab): qf[hf] = Q[qw+col][hf*32 + g*8 + j]
  bfx8 qf[2];
#pragma unroll
  for (int hf = 0; hf < 2; hf++)
    qf[hf] = *(const bfx8*)&qkv[(size_t)(qw + col) * QKV_N + hq + hf * 32 + g * 8];

  const f32x4 zero = {0.f, 0.f, 0.f, 0.f};
  f32x4 o[4];
#pragma unroll
  for (int c = 0; c < 4; c++) o[c] = zero;
  float m = -INFINITY, lsum = 0.f;

  const int qabs = qw + col;
  const int src0 = (g & 1) * 32 + col;
  const int src1 = src0 + 16;

  STAGE(0, 0);

  for (int t = 0; t < nt; t++) {
    const int cur = t & 1;
    const int kv = t * 64;
    if (t + 1 < nt) {
      STAGE(cur ^ 1, kv + 64);
      asm volatile("s_waitcnt vmcnt(4)" ::: "memory");
    } else {
      asm volatile("s_waitcnt vmcnt(0)" ::: "memory");
    }
    __builtin_amdgcn_s_barrier();

    if (kv <= qw + 15) {  // wave-uniform: skip fully-masked tiles
      bfx8 kf[4][2];
#pragma unroll
      for (int sub = 0; sub < 4; sub++) {
        int row = sub * 16 + col;
#pragma unroll
        for (int hf = 0; hf < 2; hf++)
          kf[sub][hf] = *(const bfx8*)&Ks[cur][row * 64 + (((hf << 2) | g) ^ (row & 7)) * 8];
      }

      // QK^T (pre-scaled): s[sub][r] = S^T[key=kv+sub*16+4g+r][q=col]
      f32x4 s[4];
#pragma unroll
      for (int sub = 0; sub < 4; sub++) {
        s[sub] = zero;
        s[sub] = MFMA16(kf[sub][0], qf[0], s[sub]);
        s[sub] = MFMA16(kf[sub][1], qf[1], s[sub]);
      }

      float sv[4][4];
      float tm = -INFINITY;
      if (kv + 63 <= qw) {  // fully unmasked fast path (wave-uniform)
#pragma unroll
        for (int sub = 0; sub < 4; sub++)
#pragma unroll
          for (int r = 0; r < 4; r++) {
            sv[sub][r] = s[sub][r];
            tm = fmaxf(tm, sv[sub][r]);
          }
      } else {
#pragma unroll
        for (int sub = 0; sub < 4; sub++)
#pragma unroll
          for (int r = 0; r < 4; r++) {
            int key = kv + sub * 16 + 4 * g + r;
            sv[sub][r] = (key > qabs) ? -INFINITY : s[sub][r];
            tm = fmaxf(tm, sv[sub][r]);
          }
      }
      tm = fmaxf(tm, __shfl_xor(tm, 16));
      tm = fmaxf(tm, __shfl_xor(tm, 32));

      // defer-max: only rescale when the running max grows by > 5
      if (!__all(tm <= m + 5.0f)) {
        float mnew = fmaxf(m, tm);
        float so = __expf(m - mnew);  // 0 on first tile
#pragma unroll
        for (int c = 0; c < 4; c++)
#pragma unroll
          for (int r = 0; r < 4; r++) o[c][r] *= so;
        lsum *= so;
        m = mnew;
      }

      // P = exp(sv - m), truncated to bf16; psum from the SAME truncated values
      unsigned u[4][4];
      float psum = 0.f;
#pragma unroll
      for (int sub = 0; sub < 4; sub++)
#pragma unroll
        for (int r = 0; r < 4; r++) {
          float pv = __expf(sv[sub][r] - m);
          unsigned bits = __builtin_bit_cast(unsigned, pv) & 0xFFFF0000u;
          u[sub][r] = bits;
          psum += __builtin_bit_cast(float, bits);
        }
      psum += __shfl_xor(psum, 16);
      psum += __shfl_xor(psum, 32);
      lsum += psum;

      // PV per 32-key step: build packed words, redistribute, 4 MFMA
#pragma unroll
      for (int ks = 0; ks < 2; ks++) {
        unsigned L0 = u[2 * ks][1] | (u[2 * ks][0] >> 16);
        unsigned L1 = u[2 * ks][3] | (u[2 * ks][2] >> 16);
        unsigned H0 = u[2 * ks + 1][1] | (u[2 * ks + 1][0] >> 16);
        unsigned H1 = u[2 * ks + 1][3] | (u[2 * ks + 1][2] >> 16);
        unsigned a0 = __shfl(L0, src0, 64), b0 = __shfl(H0, src0, 64);
        unsigned a1 = __shfl(L1, src0, 64), b1 = __shfl(H1, src0, 64);
        unsigned a2 = __shfl(L0, src1, 64), b2 = __shfl(H0, src1, 64);
        unsigned a3 = __shfl(L1, src1, 64), b3 = __shfl(H1, src1, 64);
        u32x4 w;
        w[0] = (g < 2) ? a0 : b0;
        w[1] = (g < 2) ? a1 : b1;
        w[2] = (g < 2) ? a2 : b2;
        w[3] = (g < 2) ? a3 : b3;
        bfx8 pf = __builtin_bit_cast(bfx8, w);
#pragma unroll
        for (int c = 0; c < 4; c++) {
          int row = c * 16 + col;
          bfx8 vtf = *(const bfx8*)&Vs[cur][row * 64 + (((ks << 2) | g) ^ (row & 7)) * 8];
          o[c] = MFMA16(vtf, pf, o[c]);
        }
      }
    }
    __syncthreads();  // reads of buf cur done before next iter restages it
  }

  float inv = 1.f / lsum;
#pragma unroll
  for (int c = 0; c < 4; c++) {
    bfx4 ov;
#pragma unroll
    for (int r = 0; r < 4; r++) ov[r] = f2bf(o[c][r] * inv);
    *(bfx4*)&yb[(size_t)(qw + col) * C_DIM + h * HD + c * 16 + g * 4] = ov;
  }
#undef STAGE
}

// ---------------- launch ----------------
extern "C" void kernel_launch(void* const* d_in, const int* in_sizes, int n_in,
                              void* d_out, int out_size, void* d_ws, size_t ws_size,
                              hipStream_t stream) {
  const float* x      = (const float*)d_in[0];
  const float* w_attn = (const float*)d_in[1];
  const float* w_proj = (const float*)d_in[2];
  float* out = (float*)d_out;

  char* ws = (char*)d_ws;
  short* xb  = (short*)(ws);                                    // 6291456 B (reused as Vt)
  short* wab = (short*)(ws + 6291456);                          // 3538944 B
  short* wpb = (short*)(ws + 6291456 + 3538944);                // 1179648 B
  short* qkv = (short*)(ws + 6291456 + 3538944 + 1179648);      // 18874368 B
  short* yb  = (short*)(ws + 6291456 + 3538944 + 1179648 + 18874368);  // 6291456 B
  short* Vt  = xb;  // xb dead after QKV GEMM

  conv_bf16_kernel<<<3072, 256, 0, stream>>>(x, xb, 786432);
  // fold softmax scale 1/8 into w_attn's Q columns (exact f32 mul before bf16 round)
  transpose_bf16_kernel<<<dim3(QKV_N / 32, C_DIM / 32), 256, 0, stream>>>(
      w_attn, wab, C_DIM, QKV_N, C_DIM, 0.125f);
  transpose_bf16_kernel<<<dim3(C_DIM / 32, C_DIM / 32), 256, 0, stream>>>(
      w_proj, wpb, C_DIM, C_DIM, 0, 1.0f);

  gemm_bf16<true><<<dim3(T_SEQ / 128, QKV_N / 128), 256, 0, stream>>>(xb, wab, (void*)qkv, T_SEQ, QKV_N, C_DIM);
  transpose_v_kernel<<<dim3(T_SEQ / 32, C_DIM / 32), 256, 0, stream>>>(qkv, Vt);
  attn_kernel<<<64 * NH, 256, 0, stream>>>(qkv, Vt, yb);
  gemm_bf16<false><<<dim3(T_SEQ / 128, C_DIM / 128), 256, 0, stream>>>(yb, wpb, (void*)out, T_SEQ, C_DIM, C_DIM);
}